// Round 2
// baseline (383.453 us; speedup 1.0000x reference)
//
#include <hip/hip_runtime.h>

#define N_NODES 2048
#define C_CH    128
#define N_SPEC  10

// Coefficient stream layout per (s,c), in floats:
//   C3 at [0, 6561)      : [abj][i]  (729 x 9)
//   C2 at [6576, 7305)   : [ab][i]   (81 x 9)
//   C1 at [7312, 7393)   : [a][i]    (9 x 9)
// stride padded to 7424 floats (29696 B, 64B-aligned blocks)
#define CSTRIDE 7424
#define C2_OFF  6576
#define C1_OFF  7312

// ws layout: counts @0 (16 ints), lists @64B (10*2048 ints), C @128KB
#define WS_C_BYTE_OFF 131072
#define WS_NEED ((size_t)WS_C_BYTE_OFF + (size_t)N_SPEC * C_CH * CSTRIDE * 4)

// ---------------------------------------------------------------------------
// Kernel 1: bucket nodes by species.
// ---------------------------------------------------------------------------
__global__ __launch_bounds__(1024) void bucket_kernel(const int* __restrict__ index,
                                                      int* __restrict__ counts,
                                                      int* __restrict__ lists) {
    __shared__ int sc[N_SPEC];
    const int tid = threadIdx.x;
    if (tid < N_SPEC) sc[tid] = 0;
    __syncthreads();
    for (int n = tid; n < N_NODES; n += blockDim.x) {
        int s = index[n];
        int pos = atomicAdd(&sc[s], 1);
        lists[s * N_NODES + pos] = n;
    }
    __syncthreads();
    if (tid < N_SPEC) counts[tid] = sc[tid];
}

// ---------------------------------------------------------------------------
struct Params {
    const float* U3[3]; const float* W3[3];
    const float* U2[3]; const float* W2[3];
    const float* U1[3]; const float* W1[3];
};

__device__ inline float dotU(const float* __restrict__ u, const float* __restrict__ w,
                             int MUL, int IRD, int il, int idx, int s, int c) {
    const float* up = u + (idx * MUL) * IRD + il;
    const float* wp = w + (s * MUL) * C_CH + c;
    float acc = 0.f;
    for (int k = 0; k < MUL; ++k) acc += up[k * IRD] * wp[k * C_CH];
    return acc;
}

// ---------------------------------------------------------------------------
// Kernel 2: build coefficient streams. Grid = N_SPEC * 32 blocks, 256 threads.
// Block covers (s, 4 channels); lanes 0..63 walk consecutive stream positions
// for one channel -> fully coalesced 256B writes per wave.
// ---------------------------------------------------------------------------
__global__ __launch_bounds__(256) void coef_kernel(Params p, float* __restrict__ C) {
    const int blk = blockIdx.x;
    const int s  = blk / 32;
    const int cg = blk % 32;
    const int c  = cg * 4 + (threadIdx.x >> 6);
    const int lane = threadIdx.x & 63;
    float* out = C + (size_t)(s * C_CH + c) * CSTRIDE;

    for (int e = lane; e < CSTRIDE; e += 64) {
        float v = 0.f;
        if (e < 6561) {                       // C3: abj in [0,729), i in [0,9)
            int abj = e / 9, i = e - abj * 9;
            if (i == 0)      v = dotU(p.U3[0], p.W3[0], 10, 1, 0,     abj, s, c);
            else if (i < 4)  v = dotU(p.U3[1], p.W3[1], 11, 3, i - 1, abj, s, c);
            else             v = dotU(p.U3[2], p.W3[2], 13, 5, i - 4, abj, s, c);
        } else if (e >= C2_OFF && e < C2_OFF + 729) {
            int idx = e - C2_OFF;
            int ab = idx / 9, i = idx - ab * 9;
            if (i == 0)      v = dotU(p.U2[0], p.W2[0], 3, 1, 0,     ab, s, c);
            else if (i < 4)  v = dotU(p.U2[1], p.W2[1], 2, 3, i - 1, ab, s, c);
            else             v = dotU(p.U2[2], p.W2[2], 3, 5, i - 4, ab, s, c);
        } else if (e >= C1_OFF && e < C1_OFF + 81) {
            int idx = e - C1_OFF;
            int a = idx / 9, i = idx - a * 9;
            if (i == 0)      v = dotU(p.U1[0], p.W1[0], 1, 1, 0,     a, s, c);
            else if (i < 4)  v = dotU(p.U1[1], p.W1[1], 1, 3, i - 1, a, s, c);
            else             v = dotU(p.U1[2], p.W1[2], 1, 5, i - 4, a, s, c);
        }
        out[e] = v;
    }
}

// dynamic index into a register array without scratch: cndmask chain
__device__ inline float selx(const float x[9], int a) {
    float r = x[0];
    r = (a == 1) ? x[1] : r;
    r = (a == 2) ? x[2] : r;
    r = (a == 3) ? x[3] : r;
    r = (a == 4) ? x[4] : r;
    r = (a == 5) ? x[5] : r;
    r = (a == 6) ? x[6] : r;
    r = (a == 7) ? x[7] : r;
    r = (a == 8) ? x[8] : r;
    return r;
}

// ---------------------------------------------------------------------------
// Kernel 3: evaluate. One block per (species, channel); coefficients read via
// block-uniform pointers -> scalar loads (SGPR), FMAs are v_fmac v,s,v.
// No LDS at all.
// ---------------------------------------------------------------------------
__global__ __launch_bounds__(128) void eval_kernel(const float* __restrict__ nf,
                                                   const int* __restrict__ counts,
                                                   const int* __restrict__ lists,
                                                   const float* __restrict__ C,
                                                   float* __restrict__ out) {
    const int s = blockIdx.x % N_SPEC;
    const int c = blockIdx.x / N_SPEC;
    const int tid = threadIdx.x;

    const float* __restrict__ Cb  = C + (size_t)(s * C_CH + c) * CSTRIDE;
    const float* __restrict__ C3p = Cb;
    const float* __restrict__ C2p = Cb + C2_OFF;
    const float* __restrict__ C1p = Cb + C1_OFF;

    const int cnt = counts[s];

    for (int base = 0; base < cnt; base += 256) {
        const int i0 = base + tid;
        const int i1 = base + 128 + tid;
        const int m0 = (i0 < cnt) ? lists[s * N_NODES + i0] : -1;
        const int m1 = (i1 < cnt) ? lists[s * N_NODES + i1] : -1;

        const float* x0p = nf + ((long)(m0 < 0 ? 0 : m0) * C_CH + c) * 9;
        const float* x1p = nf + ((long)(m1 < 0 ? 0 : m1) * C_CH + c) * 9;
        float x0[9], x1[9];
#pragma unroll
        for (int j = 0; j < 9; ++j) { x0[j] = x0p[j]; x1[j] = x1p[j]; }

        float o0[9], o1[9];
#pragma unroll
        for (int i = 0; i < 9; ++i) { o0[i] = 0.f; o1[i] = 0.f; }

#pragma unroll 1
        for (int a = 0; a < 9; ++a) {
            const float xa0 = selx(x0, a);
            const float xa1 = selx(x1, a);
            float q0[9], q1[9];
#pragma unroll
            for (int i = 0; i < 9; ++i) {
                const float cc = C1p[a * 9 + i];
                q0[i] = cc; q1[i] = cc;
            }
#pragma unroll 1
            for (int b = 0; b < 9; ++b) {
                const int ab = a * 9 + b;
                const float xb0 = selx(x0, b);
                const float xb1 = selx(x1, b);
                float t0[9], t1[9];
#pragma unroll
                for (int i = 0; i < 9; ++i) {
                    const float cc = C2p[ab * 9 + i];
                    t0[i] = cc; t1[i] = cc;
                }
#pragma unroll
                for (int j = 0; j < 9; ++j) {
                    const float* cp = C3p + (ab * 9 + j) * 9;
#pragma unroll
                    for (int i = 0; i < 9; ++i) {
                        const float cc = cp[i];
                        t0[i] += cc * x0[j];
                        t1[i] += cc * x1[j];
                    }
                }
#pragma unroll
                for (int i = 0; i < 9; ++i) {
                    q0[i] += t0[i] * xb0;
                    q1[i] += t1[i] * xb1;
                }
            }
#pragma unroll
            for (int i = 0; i < 9; ++i) {
                o0[i] += q0[i] * xa0;
                o1[i] += q1[i] * xa1;
            }
        }

        if (m0 >= 0) {
            float* op = out + ((long)m0 * C_CH + c) * 9;
#pragma unroll
            for (int i = 0; i < 9; ++i) op[i] = o0[i];
        }
        if (m1 >= 0) {
            float* op = out + ((long)m1 * C_CH + c) * 9;
#pragma unroll
            for (int i = 0; i < 9; ++i) op[i] = o1[i];
        }
    }
}

// ---------------------------------------------------------------------------
// Fallback (round-1 LDS kernel) in case ws_size is too small for the C stream.
// ---------------------------------------------------------------------------
template <int NAB, int MUL, int IRD, int IOFF>
__device__ inline void buildC(const float* __restrict__ u, const float* __restrict__ w,
                              int s, int c, float* __restrict__ sMain, float* __restrict__ sB) {
    const int tid = threadIdx.x;
    const float* wp = w + (s * MUL) * C_CH + c;
    for (int e = tid; e < NAB * IRD; e += 128) {
        int abj = e / IRD;
        int il  = e - abj * IRD;
        const float* up = u + (abj * MUL) * IRD + il;
        float acc = 0.f;
#pragma unroll
        for (int k = 0; k < MUL; ++k) acc += up[k * IRD] * wp[k * C_CH];
        int i = IOFF + il;
        if (i < 8) sMain[abj * 8 + i] = acc;
        else       sB[abj] = acc;
    }
}

__global__ __launch_bounds__(128) void sc_kernel(const float* __restrict__ nf,
                                                 const int* __restrict__ counts,
                                                 const int* __restrict__ lists,
                                                 Params p,
                                                 float* __restrict__ out) {
    __shared__ __align__(16) float sC3[729 * 8];
    __shared__ float sC3b[729];
    __shared__ __align__(16) float sC2[81 * 8];
    __shared__ float sC2b[81];
    __shared__ __align__(16) float sC1[9 * 8];
    __shared__ float sC1b[9];

    const int s = blockIdx.x % N_SPEC;
    const int c = blockIdx.x / N_SPEC;
    const int tid = threadIdx.x;

    buildC<729, 10, 1, 0>(p.U3[0], p.W3[0], s, c, sC3, sC3b);
    buildC<729, 11, 3, 1>(p.U3[1], p.W3[1], s, c, sC3, sC3b);
    buildC<729, 13, 5, 4>(p.U3[2], p.W3[2], s, c, sC3, sC3b);
    buildC<81, 3, 1, 0>(p.U2[0], p.W2[0], s, c, sC2, sC2b);
    buildC<81, 2, 3, 1>(p.U2[1], p.W2[1], s, c, sC2, sC2b);
    buildC<81, 3, 5, 4>(p.U2[2], p.W2[2], s, c, sC2, sC2b);
    buildC<9, 1, 1, 0>(p.U1[0], p.W1[0], s, c, sC1, sC1b);
    buildC<9, 1, 3, 1>(p.U1[1], p.W1[1], s, c, sC1, sC1b);
    buildC<9, 1, 5, 4>(p.U1[2], p.W1[2], s, c, sC1, sC1b);
    __syncthreads();

    const int cnt = counts[s];
    const float4* C3v = (const float4*)sC3;
    const float4* C2v = (const float4*)sC2;
    const float4* C1v = (const float4*)sC1;

    for (int base = 0; base < cnt; base += 256) {
        const int i0 = base + tid;
        const int i1 = base + 128 + tid;
        const int m0 = (i0 < cnt) ? lists[s * N_NODES + i0] : -1;
        const int m1 = (i1 < cnt) ? lists[s * N_NODES + i1] : -1;

        const float* x0p = nf + ((long)(m0 < 0 ? 0 : m0) * C_CH + c) * 9;
        const float* x1p = nf + ((long)(m1 < 0 ? 0 : m1) * C_CH + c) * 9;
        float x0[9], x1[9];
#pragma unroll
        for (int j = 0; j < 9; ++j) { x0[j] = x0p[j]; x1[j] = x1p[j]; }

        float4 o0a = {0,0,0,0}, o0b = {0,0,0,0};
        float4 o1a = {0,0,0,0}, o1b = {0,0,0,0};
        float o08 = 0.f, o18 = 0.f;

#pragma unroll 1
        for (int a = 0; a < 9; ++a) {
            const float xa0 = selx(x0, a);
            const float xa1 = selx(x1, a);
            const float4 c1a = C1v[a * 2], c1b = C1v[a * 2 + 1];
            const float  c18 = sC1b[a];
            float4 q0a = c1a, q0b = c1b; float q08 = c18;
            float4 q1a = c1a, q1b = c1b; float q18 = c18;
#pragma unroll
            for (int b = 0; b < 9; ++b) {
                const int ab = a * 9 + b;
                const float4 c2a = C2v[ab * 2], c2b = C2v[ab * 2 + 1];
                const float  c28 = sC2b[ab];
                float4 t0a = c2a, t0b = c2b; float t08 = c28;
                float4 t1a = c2a, t1b = c2b; float t18 = c28;
#pragma unroll
                for (int j = 0; j < 9; ++j) {
                    const int abj = ab * 9 + j;
                    const float4 ca = C3v[abj * 2];
                    const float4 cb = C3v[abj * 2 + 1];
                    const float  c8 = sC3b[abj];
                    t0a += ca * x0[j]; t0b += cb * x0[j]; t08 += c8 * x0[j];
                    t1a += ca * x1[j]; t1b += cb * x1[j]; t18 += c8 * x1[j];
                }
                q0a += t0a * x0[b]; q0b += t0b * x0[b]; q08 += t08 * x0[b];
                q1a += t1a * x1[b]; q1b += t1b * x1[b]; q18 += t18 * x1[b];
            }
            o0a += q0a * xa0; o0b += q0b * xa0; o08 += q08 * xa0;
            o1a += q1a * xa1; o1b += q1b * xa1; o18 += q18 * xa1;
        }

        if (m0 >= 0) {
            float* op = out + ((long)m0 * C_CH + c) * 9;
            op[0]=o0a.x; op[1]=o0a.y; op[2]=o0a.z; op[3]=o0a.w;
            op[4]=o0b.x; op[5]=o0b.y; op[6]=o0b.z; op[7]=o0b.w;
            op[8]=o08;
        }
        if (m1 >= 0) {
            float* op = out + ((long)m1 * C_CH + c) * 9;
            op[0]=o1a.x; op[1]=o1a.y; op[2]=o1a.z; op[3]=o1a.w;
            op[4]=o1b.x; op[5]=o1b.y; op[6]=o1b.z; op[7]=o1b.w;
            op[8]=o18;
        }
    }
}

// ---------------------------------------------------------------------------
extern "C" void kernel_launch(void* const* d_in, const int* in_sizes, int n_in,
                              void* d_out, int out_size, void* d_ws, size_t ws_size,
                              hipStream_t stream) {
    const float* nf  = (const float*)d_in[0];
    const int* index = (const int*)d_in[1];

    Params p;
    p.U3[0] = (const float*)d_in[2];  p.W3[0] = (const float*)d_in[3];
    p.U3[1] = (const float*)d_in[4];  p.W3[1] = (const float*)d_in[5];
    p.U3[2] = (const float*)d_in[6];  p.W3[2] = (const float*)d_in[7];
    p.U2[0] = (const float*)d_in[8];  p.W2[0] = (const float*)d_in[9];
    p.U2[1] = (const float*)d_in[10]; p.W2[1] = (const float*)d_in[11];
    p.U2[2] = (const float*)d_in[12]; p.W2[2] = (const float*)d_in[13];
    p.U1[0] = (const float*)d_in[14]; p.W1[0] = (const float*)d_in[15];
    p.U1[1] = (const float*)d_in[16]; p.W1[1] = (const float*)d_in[17];
    p.U1[2] = (const float*)d_in[18]; p.W1[2] = (const float*)d_in[19];

    int* counts = (int*)d_ws;
    int* lists  = (int*)d_ws + 16;

    bucket_kernel<<<1, 1024, 0, stream>>>(index, counts, lists);

    if (ws_size >= WS_NEED) {
        float* C = (float*)((char*)d_ws + WS_C_BYTE_OFF);
        coef_kernel<<<N_SPEC * 32, 256, 0, stream>>>(p, C);
        eval_kernel<<<N_SPEC * C_CH, 128, 0, stream>>>(nf, counts, lists, C, (float*)d_out);
    } else {
        sc_kernel<<<N_SPEC * C_CH, 128, 0, stream>>>(nf, counts, lists, p, (float*)d_out);
    }
}

// Round 3
// 357.045 us; speedup vs baseline: 1.0740x; 1.0740x over previous
//
#include <hip/hip_runtime.h>

#define N_NODES 2048
#define C_CH    128
#define N_SPEC  10

// ---------------------------------------------------------------------------
// Kernel 1: bucket nodes by species.
// ---------------------------------------------------------------------------
__global__ __launch_bounds__(1024) void bucket_kernel(const int* __restrict__ index,
                                                      int* __restrict__ counts,
                                                      int* __restrict__ lists) {
    __shared__ int sc[N_SPEC];
    const int tid = threadIdx.x;
    if (tid < N_SPEC) sc[tid] = 0;
    __syncthreads();
    for (int n = tid; n < N_NODES; n += blockDim.x) {
        int s = index[n];
        int pos = atomicAdd(&sc[s], 1);
        lists[s * N_NODES + pos] = n;
    }
    __syncthreads();
    if (tid < N_SPEC) counts[tid] = sc[tid];
}

// ---------------------------------------------------------------------------
struct Params {
    const float* U3[3]; const float* W3[3];
    const float* U2[3]; const float* W2[3];
    const float* U1[3]; const float* W1[3];
};

template <int MUL, int IRD>
__device__ __forceinline__ float dotc(const float* __restrict__ up, const float* __restrict__ wp) {
    float acc = 0.f;
#pragma unroll
    for (int k = 0; k < MUL; ++k)
        acc = __builtin_fmaf(up[k * IRD], wp[k * C_CH], acc);
    return acc;
}

__device__ __forceinline__ unsigned short f2bf(float f) {   // RNE f32->bf16
    unsigned u = __float_as_uint(f);
    unsigned r = ((u >> 16) & 1u) + 0x7fffu;
    return (unsigned short)((u + r) >> 16);
}
__device__ __forceinline__ float bf_lo(unsigned u) { return __uint_as_float(u << 16); }
__device__ __forceinline__ float bf_hi(unsigned u) { return __uint_as_float(u & 0xffff0000u); }
__device__ __forceinline__ float bf_up(unsigned short h) { return __uint_as_float(((unsigned)h) << 16); }

// dynamic index into a register array without scratch: cndmask chain
__device__ __forceinline__ float selx(const float x[9], int a) {
    float r = x[0];
    r = (a == 1) ? x[1] : r;
    r = (a == 2) ? x[2] : r;
    r = (a == 3) ? x[3] : r;
    r = (a == 4) ? x[4] : r;
    r = (a == 5) ? x[5] : r;
    r = (a == 6) ? x[6] : r;
    r = (a == 7) ? x[7] : r;
    r = (a == 8) ? x[8] : r;
    return r;
}

// ---------------------------------------------------------------------------
// Kernel 2: fused build + eval. One 64-thread block (1 wave) per (species,
// channel). C3 stored bf16-packed in LDS ([abj] -> 16B holding i0..7, plus a
// separate i8 plane); C2/C1 stay f32. Each thread evaluates 4 nodes so one
// ds_read_b128 feeds 36 FMAs -> VALU-bound, not LDS-pipe-bound.
// ---------------------------------------------------------------------------
__global__ __launch_bounds__(64, 2) void sc2_kernel(const float* __restrict__ nf,
                                                    const int* __restrict__ counts,
                                                    const int* __restrict__ lists,
                                                    Params p,
                                                    float* __restrict__ out) {
    __shared__ __align__(16) unsigned short sC3[729 * 8];  // bf16, [abj][i0..7]
    __shared__ __align__(4)  unsigned short sC3b[730];     // bf16, [abj] i==8
    __shared__ __align__(16) float sC2[81 * 8];            // f32,  [ab][i0..7]
    __shared__ float sC2b[81];
    __shared__ __align__(16) float sC1[9 * 8];
    __shared__ float sC1b[9];
    // LDS ~16.4 KB -> 9 blocks/CU (LDS), 8 (VGPR) -> ~8 waves/CU

    const int s = blockIdx.x % N_SPEC;
    const int c = blockIdx.x / N_SPEC;
    const int tid = threadIdx.x;

    // ---- build C3 (bf16) ----
    for (int e = tid; e < 6561; e += 64) {
        int abj = e / 9; int i = e - abj * 9;
        float v;
        if (i == 0)     v = dotc<10, 1>(p.U3[0] + abj * 10,           p.W3[0] + (s * 10) * C_CH + c);
        else if (i < 4) v = dotc<11, 3>(p.U3[1] + abj * 33 + (i - 1), p.W3[1] + (s * 11) * C_CH + c);
        else            v = dotc<13, 5>(p.U3[2] + abj * 65 + (i - 4), p.W3[2] + (s * 13) * C_CH + c);
        if (i < 8) sC3[abj * 8 + i] = f2bf(v); else sC3b[abj] = f2bf(v);
    }
    // ---- build C2 (f32) ----
    for (int e = tid; e < 729; e += 64) {
        int ab = e / 9; int i = e - ab * 9;
        float v;
        if (i == 0)     v = dotc<3, 1>(p.U2[0] + ab * 3,            p.W2[0] + (s * 3) * C_CH + c);
        else if (i < 4) v = dotc<2, 3>(p.U2[1] + ab * 6 + (i - 1),  p.W2[1] + (s * 2) * C_CH + c);
        else            v = dotc<3, 5>(p.U2[2] + ab * 15 + (i - 4), p.W2[2] + (s * 3) * C_CH + c);
        if (i < 8) sC2[ab * 8 + i] = v; else sC2b[ab] = v;
    }
    // ---- build C1 (f32) ----
    for (int e = tid; e < 81; e += 64) {
        int a = e / 9; int i = e - a * 9;
        float v;
        if (i == 0)     v = dotc<1, 1>(p.U1[0] + a,               p.W1[0] + s * C_CH + c);
        else if (i < 4) v = dotc<1, 3>(p.U1[1] + a * 3 + (i - 1), p.W1[1] + s * C_CH + c);
        else            v = dotc<1, 5>(p.U1[2] + a * 5 + (i - 4), p.W1[2] + s * C_CH + c);
        if (i < 8) sC1[a * 8 + i] = v; else sC1b[a] = v;
    }
    __syncthreads();

    const int cnt = counts[s];
    const uint4*  C3v = (const uint4*)sC3;
    const float4* C2v = (const float4*)sC2;
    const float4* C1v = (const float4*)sC1;

    for (int base = 0; base < cnt; base += 256) {
        int m[4];
        float x[4][9];
#pragma unroll
        for (int pn = 0; pn < 4; ++pn) {
            int idx = base + pn * 64 + tid;
            m[pn] = (idx < cnt) ? lists[s * N_NODES + idx] : -1;
            const float* xp = nf + ((long)(m[pn] < 0 ? 0 : m[pn]) * C_CH + c) * 9;
#pragma unroll
            for (int j = 0; j < 9; ++j) x[pn][j] = xp[j];
        }

        float o[4][9];
#pragma unroll
        for (int pn = 0; pn < 4; ++pn)
#pragma unroll
            for (int i = 0; i < 9; ++i) o[pn][i] = 0.f;

#pragma unroll 1
        for (int a = 0; a < 9; ++a) {
            float xa[4];
#pragma unroll
            for (int pn = 0; pn < 4; ++pn) xa[pn] = selx(x[pn], a);

            float c1[9];
            {
                float4 lo = C1v[a * 2], hi = C1v[a * 2 + 1];
                c1[0] = lo.x; c1[1] = lo.y; c1[2] = lo.z; c1[3] = lo.w;
                c1[4] = hi.x; c1[5] = hi.y; c1[6] = hi.z; c1[7] = hi.w;
                c1[8] = sC1b[a];
            }
            float q[4][9];
#pragma unroll
            for (int pn = 0; pn < 4; ++pn)
#pragma unroll
                for (int i = 0; i < 9; ++i) q[pn][i] = c1[i];

#pragma unroll 1
            for (int b = 0; b < 9; ++b) {
                const int ab = a * 9 + b;
                float xb[4];
#pragma unroll
                for (int pn = 0; pn < 4; ++pn) xb[pn] = selx(x[pn], b);

                float c2[9];
                {
                    float4 lo = C2v[ab * 2], hi = C2v[ab * 2 + 1];
                    c2[0] = lo.x; c2[1] = lo.y; c2[2] = lo.z; c2[3] = lo.w;
                    c2[4] = hi.x; c2[5] = hi.y; c2[6] = hi.z; c2[7] = hi.w;
                    c2[8] = sC2b[ab];
                }

                float t[4][9];
                {   // j = 0: fold C2 init via 3-operand fma
                    uint4 r = C3v[ab * 9];
                    float cc[9];
                    cc[0] = bf_lo(r.x); cc[1] = bf_hi(r.x);
                    cc[2] = bf_lo(r.y); cc[3] = bf_hi(r.y);
                    cc[4] = bf_lo(r.z); cc[5] = bf_hi(r.z);
                    cc[6] = bf_lo(r.w); cc[7] = bf_hi(r.w);
                    cc[8] = bf_up(sC3b[ab * 9]);
#pragma unroll
                    for (int pn = 0; pn < 4; ++pn)
#pragma unroll
                        for (int i = 0; i < 9; ++i)
                            t[pn][i] = __builtin_fmaf(cc[i], x[pn][0], c2[i]);
                }
#pragma unroll
                for (int j = 1; j < 9; ++j) {
                    uint4 r = C3v[ab * 9 + j];
                    float cc[9];
                    cc[0] = bf_lo(r.x); cc[1] = bf_hi(r.x);
                    cc[2] = bf_lo(r.y); cc[3] = bf_hi(r.y);
                    cc[4] = bf_lo(r.z); cc[5] = bf_hi(r.z);
                    cc[6] = bf_lo(r.w); cc[7] = bf_hi(r.w);
                    cc[8] = bf_up(sC3b[ab * 9 + j]);
#pragma unroll
                    for (int pn = 0; pn < 4; ++pn)
#pragma unroll
                        for (int i = 0; i < 9; ++i)
                            t[pn][i] = __builtin_fmaf(cc[i], x[pn][j], t[pn][i]);
                }
#pragma unroll
                for (int pn = 0; pn < 4; ++pn)
#pragma unroll
                    for (int i = 0; i < 9; ++i)
                        q[pn][i] = __builtin_fmaf(t[pn][i], xb[pn], q[pn][i]);
            }
#pragma unroll
            for (int pn = 0; pn < 4; ++pn)
#pragma unroll
                for (int i = 0; i < 9; ++i)
                    o[pn][i] = __builtin_fmaf(q[pn][i], xa[pn], o[pn][i]);
        }

#pragma unroll
        for (int pn = 0; pn < 4; ++pn) {
            if (m[pn] >= 0) {
                float* op = out + ((long)m[pn] * C_CH + c) * 9;
#pragma unroll
                for (int i = 0; i < 9; ++i) op[i] = o[pn][i];
            }
        }
    }
}

// ---------------------------------------------------------------------------
extern "C" void kernel_launch(void* const* d_in, const int* in_sizes, int n_in,
                              void* d_out, int out_size, void* d_ws, size_t ws_size,
                              hipStream_t stream) {
    const float* nf  = (const float*)d_in[0];
    const int* index = (const int*)d_in[1];

    Params p;
    p.U3[0] = (const float*)d_in[2];  p.W3[0] = (const float*)d_in[3];
    p.U3[1] = (const float*)d_in[4];  p.W3[1] = (const float*)d_in[5];
    p.U3[2] = (const float*)d_in[6];  p.W3[2] = (const float*)d_in[7];
    p.U2[0] = (const float*)d_in[8];  p.W2[0] = (const float*)d_in[9];
    p.U2[1] = (const float*)d_in[10]; p.W2[1] = (const float*)d_in[11];
    p.U2[2] = (const float*)d_in[12]; p.W2[2] = (const float*)d_in[13];
    p.U1[0] = (const float*)d_in[14]; p.W1[0] = (const float*)d_in[15];
    p.U1[1] = (const float*)d_in[16]; p.W1[1] = (const float*)d_in[17];
    p.U1[2] = (const float*)d_in[18]; p.W1[2] = (const float*)d_in[19];

    int* counts = (int*)d_ws;
    int* lists  = (int*)d_ws + 16;

    bucket_kernel<<<1, 1024, 0, stream>>>(index, counts, lists);
    sc2_kernel<<<N_SPEC * C_CH, 64, 0, stream>>>(nf, counts, lists, p, (float*)d_out);
}